// Round 1
// baseline (1984.556 us; speedup 1.0000x reference)
//
#include <hip/hip_runtime.h>
#include <cstdint>

typedef __attribute__((ext_vector_type(8))) short short8;
typedef __attribute__((ext_vector_type(4))) float f32x4;

#define LOG2E 1.44269504088896340736f

__device__ __forceinline__ unsigned short f2bf(float x) {
  union { float f; unsigned u; } c; c.f = x;
  unsigned r = c.u + 0x7fffu + ((c.u >> 16) & 1u);
  return (unsigned short)(r >> 16);
}

// ---------------------------------------------------------------------------
// K0: fp32 -> bf16 weight conversion (Wq, Wk)
// ---------------------------------------------------------------------------
__global__ void cvt_bf16(const float* __restrict__ src, unsigned short* __restrict__ dst, int n4) {
  int i = blockIdx.x * 256 + threadIdx.x;
  if (i >= n4) return;
  float4 v = ((const float4*)src)[i];
  ushort4 o;
  o.x = f2bf(v.x); o.y = f2bf(v.y); o.z = f2bf(v.z); o.w = f2bf(v.w);
  ((ushort4*)dst)[i] = o;
}

// ---------------------------------------------------------------------------
// Shared MFMA core: 128x128 (or 64x256) tile out of LDS tiles with pitch 72
// A rows = m (lane&15 within 16-tile), B rows = n; both read 16B contiguous.
// ---------------------------------------------------------------------------
__device__ __forceinline__ void mfma_tile(const unsigned short* Alds, const unsigned short* Blds,
                                          int ihalf, int jhalf, int q, int ln, f32x4 acc[4][4]) {
#pragma unroll
  for (int ks = 0; ks < 2; ++ks) {
    short8 af[4], bfr[4];
#pragma unroll
    for (int mt = 0; mt < 4; ++mt)
      af[mt] = *(const short8*)(&Alds[(ihalf * 64 + mt * 16 + ln) * 72 + ks * 32 + q * 8]);
#pragma unroll
    for (int nt = 0; nt < 4; ++nt)
      bfr[nt] = *(const short8*)(&Blds[(jhalf * 64 + nt * 16 + ln) * 72 + ks * 32 + q * 8]);
#pragma unroll
    for (int mt = 0; mt < 4; ++mt)
#pragma unroll
      for (int nt = 0; nt < 4; ++nt)
        acc[mt][nt] = __builtin_amdgcn_mfma_f32_16x16x32_bf16(af[mt], bfr[nt], acc[mt][nt], 0, 0, 0);
  }
}

// stage a [128 rows][64 cols] bf16 tile (src pitch 256) into LDS pitch 72
__device__ __forceinline__ void stage128(unsigned short* __restrict__ lds,
                                         const unsigned short* __restrict__ src) {
  const int t = threadIdx.x;
#pragma unroll
  for (int p = 0; p < 4; ++p) {
    int s = t + 256 * p;
    int row = s >> 3, sl = s & 7;
    *(uint4*)(&lds[row * 72 + sl * 8]) = *(const uint4*)(&src[row * 256 + sl * 8]);
  }
}

// ---------------------------------------------------------------------------
// K1: projection  Out[b][sp][co] = sum_ci In[b][ci][sp] * W[co][ci] + bias[co]
// M = 64 spatial rows per WG, N = 256 channels (one 64-wide slice per wave).
// ---------------------------------------------------------------------------
__global__ __launch_bounds__(256, 2) void proj_kernel(
    const float* __restrict__ In, const unsigned short* __restrict__ Wbf,
    const float* __restrict__ bias, unsigned short* __restrict__ Out, int Kdim) {
  __shared__ unsigned short Alds[64 * 72];
  __shared__ unsigned short Blds[256 * 72];
  const int b = blockIdx.y, sp0 = blockIdx.x * 64;
  const int t = threadIdx.x, w = t >> 6, lane = t & 63, q = lane >> 4, ln = lane & 15;
  f32x4 acc[4][4] = {};
  const int nch = Kdim >> 6;
  for (int ch = 0; ch < nch; ++ch) {
    const int ci0 = ch * 64;
    // stage B = W rows [256 co][64 ci]
#pragma unroll
    for (int p = 0; p < 8; ++p) {
      int s = t + 256 * p;
      int row = s >> 3, sl = s & 7;
      *(uint4*)(&Blds[row * 72 + sl * 8]) = *(const uint4*)(&Wbf[(size_t)row * Kdim + ci0 + sl * 8]);
    }
    // stage A = In^T tile [64 sp][64 ci] with transpose+convert
    {
      const int cp = t & 31, spg = t >> 5;
      const float* r0 = In + ((size_t)b * Kdim + ci0 + 2 * cp) * 4096 + sp0 + spg * 8;
      const float* r1 = r0 + 4096;
      float4 a0 = *(const float4*)(r0);
      float4 a1 = *(const float4*)(r0 + 4);
      float4 b0 = *(const float4*)(r1);
      float4 b1 = *(const float4*)(r1 + 4);
      float va[8] = {a0.x, a0.y, a0.z, a0.w, a1.x, a1.y, a1.z, a1.w};
      float vb[8] = {b0.x, b0.y, b0.z, b0.w, b1.x, b1.y, b1.z, b1.w};
#pragma unroll
      for (int k2 = 0; k2 < 8; ++k2) {
        unsigned u0 = f2bf(va[k2]), u1 = f2bf(vb[k2]);
        *(unsigned*)(&Alds[(spg * 8 + k2) * 72 + 2 * cp]) = u0 | (u1 << 16);
      }
    }
    __syncthreads();
    mfma_tile(Alds, Blds, 0, w, q, ln, acc);
    __syncthreads();
  }
  // epilogue: add bias, store bf16 [b][sp][co]
#pragma unroll
  for (int nt = 0; nt < 4; ++nt) {
    int co = w * 64 + nt * 16 + ln;
    float bv = bias[co];
#pragma unroll
    for (int mt = 0; mt < 4; ++mt)
#pragma unroll
      for (int r = 0; r < 4; ++r) {
        int sp = sp0 + mt * 16 + q * 4 + r;
        Out[((size_t)b * 4096 + sp) * 256 + co] = f2bf(acc[mt][nt][r] + bv);
      }
  }
}

// ---------------------------------------------------------------------------
// K2: row stats. WG owns (b, 128 query rows); loops 32 key tiles of 128.
// S_ij = sum_c qt[i][c]*kt[j][c]. Online max/sumexp (exp2 domain).
// ---------------------------------------------------------------------------
__global__ __launch_bounds__(256, 2) void attn_rowstats(
    const unsigned short* __restrict__ qt, const unsigned short* __restrict__ kt,
    float* __restrict__ row_m, float* __restrict__ row_l) {
  __shared__ unsigned short Alds[128 * 72];
  __shared__ unsigned short Blds[128 * 72];
  __shared__ float m_run[128], l_run[128], tred[2][128];
  const int b = blockIdx.y, i0 = blockIdx.x * 128;
  const int t = threadIdx.x, w = t >> 6, lane = t & 63, q = lane >> 4, ln = lane & 15;
  const int ihalf = w >> 1, jhalf = w & 1;
  const unsigned short* qbase = qt + ((size_t)b * 4096 + i0) * 256;
  const unsigned short* kbase = kt + (size_t)b * 4096 * 256;
  if (t < 128) { m_run[t] = -1e30f; l_run[t] = 0.f; }
  __syncthreads();
  for (int jt = 0; jt < 32; ++jt) {
    f32x4 acc[4][4] = {};
    const unsigned short* kb = kbase + (size_t)jt * 128 * 256;
    for (int ch = 0; ch < 4; ++ch) {
      stage128(Alds, qbase + ch * 64);
      stage128(Blds, kb + ch * 64);
      __syncthreads();
      mfma_tile(Alds, Blds, ihalf, jhalf, q, ln, acc);
      __syncthreads();
    }
    // phase 1: per-row max of this 128-wide tile
#pragma unroll
    for (int mt = 0; mt < 4; ++mt)
#pragma unroll
      for (int r = 0; r < 4; ++r) {
        float v = fmaxf(fmaxf(acc[mt][0][r], acc[mt][1][r]), fmaxf(acc[mt][2][r], acc[mt][3][r]));
        v = fmaxf(v, __shfl_xor(v, 1)); v = fmaxf(v, __shfl_xor(v, 2));
        v = fmaxf(v, __shfl_xor(v, 4)); v = fmaxf(v, __shfl_xor(v, 8));
        if (ln == 0) tred[jhalf][ihalf * 64 + mt * 16 + q * 4 + r] = v;
      }
    __syncthreads();
    if (t < 128) {
      float mt_ = fmaxf(tred[0][t], tred[1][t]);
      float mo = m_run[t], mn = fmaxf(mo, mt_);
      l_run[t] *= exp2f((mo - mn) * LOG2E);
      m_run[t] = mn;
    }
    __syncthreads();
    // phase 3: sum exp with new max
#pragma unroll
    for (int mt = 0; mt < 4; ++mt)
#pragma unroll
      for (int r = 0; r < 4; ++r) {
        float mrow = m_run[ihalf * 64 + mt * 16 + q * 4 + r];
        float v = exp2f((acc[mt][0][r] - mrow) * LOG2E) + exp2f((acc[mt][1][r] - mrow) * LOG2E)
                + exp2f((acc[mt][2][r] - mrow) * LOG2E) + exp2f((acc[mt][3][r] - mrow) * LOG2E);
        v += __shfl_xor(v, 1); v += __shfl_xor(v, 2);
        v += __shfl_xor(v, 4); v += __shfl_xor(v, 8);
        if (ln == 0) tred[jhalf][ihalf * 64 + mt * 16 + q * 4 + r] = v;
      }
    __syncthreads();
    if (t < 128) l_run[t] += tred[0][t] + tred[1][t];
    __syncthreads();
  }
  if (t < 128) {
    row_m[b * 4096 + i0 + t] = m_run[t];
    row_l[b * 4096 + i0 + t] = l_run[t];
  }
}

// ---------------------------------------------------------------------------
// K3: column sums. WG owns (b, 128 key cols); loops 32 query tiles.
// s[j] += sum_i exp2((S_ij - m_i)*log2e) / l_i
// ---------------------------------------------------------------------------
__global__ __launch_bounds__(256, 2) void attn_colsum(
    const unsigned short* __restrict__ qt, const unsigned short* __restrict__ kt,
    const float* __restrict__ row_m, const float* __restrict__ row_l,
    float* __restrict__ s_col) {
  __shared__ unsigned short Alds[128 * 72];
  __shared__ unsigned short Blds[128 * 72];
  __shared__ float mi[128], li[128], s_acc[2][128];
  const int b = blockIdx.y, j0 = blockIdx.x * 128;
  const int t = threadIdx.x, w = t >> 6, lane = t & 63, q = lane >> 4, ln = lane & 15;
  const int ihalf = w >> 1, jhalf = w & 1;
  const unsigned short* kb = kt + ((size_t)b * 4096 + j0) * 256;
  ((float*)s_acc)[t] = 0.f;
  __syncthreads();
  for (int it = 0; it < 32; ++it) {
    if (t < 128) {
      mi[t] = row_m[b * 4096 + it * 128 + t];
      li[t] = 1.0f / row_l[b * 4096 + it * 128 + t];
    }
    f32x4 acc[4][4] = {};
    const unsigned short* qb = qt + ((size_t)b * 4096 + it * 128) * 256;
    for (int ch = 0; ch < 4; ++ch) {
      stage128(Alds, qb + ch * 64);
      stage128(Blds, kb + ch * 64);
      __syncthreads();
      mfma_tile(Alds, Blds, ihalf, jhalf, q, ln, acc);
      __syncthreads();
    }
#pragma unroll
    for (int nt = 0; nt < 4; ++nt) {
      float v = 0.f;
#pragma unroll
      for (int mt = 0; mt < 4; ++mt)
#pragma unroll
        for (int r = 0; r < 4; ++r) {
          int il = ihalf * 64 + mt * 16 + q * 4 + r;
          v += exp2f((acc[mt][nt][r] - mi[il]) * LOG2E) * li[il];
        }
      v += __shfl_xor(v, 16); v += __shfl_xor(v, 32);
      if (q == 0) s_acc[ihalf][jhalf * 64 + nt * 16 + ln] += v;
    }
    __syncthreads();
  }
  if (t < 128) s_col[b * 4096 + j0 + t] = s_acc[0][t] + s_acc[1][t];
}

// ---------------------------------------------------------------------------
// sbar[b] = sum_n s[b][n] / 4096
// ---------------------------------------------------------------------------
__global__ void sbar_kernel(const float* __restrict__ s_col, float* __restrict__ sbar) {
  const int b = blockIdx.x, t = threadIdx.x;
  float v = 0.f;
  for (int k = 0; k < 16; ++k) v += s_col[b * 4096 + t + 256 * k];
  for (int m = 1; m < 64; m <<= 1) v += __shfl_xor(v, m);
  __shared__ float red[4];
  if ((t & 63) == 0) red[t >> 6] = v;
  __syncthreads();
  if (t == 0) sbar[b] = (red[0] + red[1] + red[2] + red[3]) * (1.f / 4096.f);
}

// ---------------------------------------------------------------------------
// K4: pooling. chunk<4 -> img channels (u & imean); else pc2d channels (t).
// ---------------------------------------------------------------------------
__global__ void pool_kernel(const float* __restrict__ img, const float* __restrict__ pc2d,
                            const float* __restrict__ s_col, float* __restrict__ u_pool,
                            float* __restrict__ imean, float* __restrict__ t_pool) {
  const int b = blockIdx.y, chunk = blockIdx.x;
  const int t = threadIdx.x, ch_l = t >> 2, j = t & 3;
  const bool isimg = chunk < 4;
  int ch;
  const float4* row4;
  if (isimg) {
    ch = chunk * 64 + ch_l;
    row4 = (const float4*)(img + ((size_t)b * 256 + ch) * 4096);
  } else {
    ch = (chunk - 4) * 64 + ch_l;
    row4 = (const float4*)(pc2d + ((size_t)b * 2048 + ch) * 4096);
  }
  const float4* s4 = (const float4*)(s_col + b * 4096);
  float accd = 0.f, accs = 0.f;
  for (int kk = 0; kk < 256; ++kk) {
    float4 x = row4[j + 4 * kk];
    float4 sv = s4[j + 4 * kk];
    accd += x.x * sv.x + x.y * sv.y + x.z * sv.z + x.w * sv.w;
    accs += x.x + x.y + x.z + x.w;
  }
  accd += __shfl_xor(accd, 1); accd += __shfl_xor(accd, 2);
  accs += __shfl_xor(accs, 1); accs += __shfl_xor(accs, 2);
  if (j == 0) {
    if (isimg) {
      u_pool[b * 256 + ch] = accd * (1.f / 4096.f);
      imean[b * 256 + ch] = accs * (1.f / 4096.f);
    } else {
      t_pool[b * 2048 + ch] = accd * (1.f / 4096.f);
    }
  }
}

// ---------------------------------------------------------------------------
// img_feat -> fused[0:256]
// ---------------------------------------------------------------------------
__global__ void imgfeat_kernel(const float* __restrict__ Wvi, const float* __restrict__ bvi,
                               const float* __restrict__ gamma1, const float* __restrict__ u_pool,
                               const float* __restrict__ imean, const float* __restrict__ sbar,
                               float* __restrict__ fused) {
  const int t = threadIdx.x;
  const int co = blockIdx.x * 64 + (t >> 2), j = t & 3;
  float acc[16];
#pragma unroll
  for (int b = 0; b < 16; ++b) acc[b] = 0.f;
  const float4* w4 = (const float4*)(Wvi + (size_t)co * 256);
  for (int kk = 0; kk < 16; ++kk) {
    float4 wv = w4[j + 4 * kk];
#pragma unroll
    for (int b = 0; b < 16; ++b) {
      float4 uv = ((const float4*)(u_pool + b * 256))[j + 4 * kk];
      acc[b] += wv.x * uv.x + wv.y * uv.y + wv.z * uv.z + wv.w * uv.w;
    }
  }
#pragma unroll
  for (int b = 0; b < 16; ++b) { acc[b] += __shfl_xor(acc[b], 1); acc[b] += __shfl_xor(acc[b], 2); }
  if (j == 0) {
    float g = gamma1[0], bv = bvi[co];
#pragma unroll
    for (int b = 0; b < 16; ++b)
      fused[b * 2304 + co] = g * (acc[b] + bv * sbar[b]) + imean[b * 256 + co];
  }
}

// ---------------------------------------------------------------------------
// pc_feat -> fused[256:2304]
// ---------------------------------------------------------------------------
__global__ void pcfeat_kernel(const float* __restrict__ Wvp, const float* __restrict__ bvp,
                              const float* __restrict__ t_pool, const float* __restrict__ sbar,
                              float* __restrict__ fused) {
  const int t = threadIdx.x;
  const int co = blockIdx.x * 64 + (t >> 2), j = t & 3;
  float acc[16];
#pragma unroll
  for (int b = 0; b < 16; ++b) acc[b] = 0.f;
  const float4* w4 = (const float4*)(Wvp + (size_t)co * 2048);
  for (int kk = 0; kk < 128; ++kk) {
    float4 wv = w4[j + 4 * kk];
#pragma unroll
    for (int b = 0; b < 16; ++b) {
      float4 tv = ((const float4*)(t_pool + b * 2048))[j + 4 * kk];
      acc[b] += wv.x * tv.x + wv.y * tv.y + wv.z * tv.z + wv.w * tv.w;
    }
  }
#pragma unroll
  for (int b = 0; b < 16; ++b) { acc[b] += __shfl_xor(acc[b], 1); acc[b] += __shfl_xor(acc[b], 2); }
  if (j == 0) {
    float bv = bvp[co];
#pragma unroll
    for (int b = 0; b < 16; ++b)
      fused[b * 2304 + 256 + co] = acc[b] + bv * sbar[b];
  }
}

// ---------------------------------------------------------------------------
// h = relu(fused @ W1^T + b1)
// ---------------------------------------------------------------------------
__global__ void head1_kernel(const float* __restrict__ W1, const float* __restrict__ b1,
                             const float* __restrict__ fused, float* __restrict__ h) {
  const int t = threadIdx.x;
  const int o = blockIdx.x * 64 + (t >> 2), j = t & 3;
  float acc[16];
#pragma unroll
  for (int b = 0; b < 16; ++b) acc[b] = 0.f;
  const float4* w4 = (const float4*)(W1 + (size_t)o * 2304);
  for (int kk = 0; kk < 144; ++kk) {
    float4 wv = w4[j + 4 * kk];
#pragma unroll
    for (int b = 0; b < 16; ++b) {
      float4 fv = ((const float4*)(fused + b * 2304))[j + 4 * kk];
      acc[b] += wv.x * fv.x + wv.y * fv.y + wv.z * fv.z + wv.w * fv.w;
    }
  }
#pragma unroll
  for (int b = 0; b < 16; ++b) { acc[b] += __shfl_xor(acc[b], 1); acc[b] += __shfl_xor(acc[b], 2); }
  if (j == 0) {
    float bv = b1[o];
#pragma unroll
    for (int b = 0; b < 16; ++b) h[b * 1024 + o] = fmaxf(acc[b] + bv, 0.f);
  }
}

// ---------------------------------------------------------------------------
// logits + log_softmax -> out[b][40]
// ---------------------------------------------------------------------------
__global__ void head2_kernel(const float* __restrict__ W2, const float* __restrict__ b2,
                             const float* __restrict__ h, float* __restrict__ out) {
  const int b = blockIdx.x, t = threadIdx.x;
  __shared__ float logit[40];
  __shared__ float red[4];
  float4 hv = ((const float4*)(h + b * 1024))[t];
  for (int c = 0; c < 40; ++c) {
    float4 wv = ((const float4*)(W2 + (size_t)c * 1024))[t];
    float p = wv.x * hv.x + wv.y * hv.y + wv.z * hv.z + wv.w * hv.w;
    for (int m = 1; m < 64; m <<= 1) p += __shfl_xor(p, m);
    if ((t & 63) == 0) red[t >> 6] = p;
    __syncthreads();
    if (t == 0) logit[c] = red[0] + red[1] + red[2] + red[3] + b2[c];
    __syncthreads();
  }
  if (t == 0) {
    float mx = -1e30f;
    for (int c = 0; c < 40; ++c) mx = fmaxf(mx, logit[c]);
    float s = 0.f;
    for (int c = 0; c < 40; ++c) s += expf(logit[c] - mx);
    float ls = logf(s);
    for (int c = 0; c < 40; ++c) out[b * 40 + c] = logit[c] - mx - ls;
  }
}

// ---------------------------------------------------------------------------
extern "C" void kernel_launch(void* const* d_in, const int* in_sizes, int n_in,
                              void* d_out, int out_size, void* d_ws, size_t ws_size,
                              hipStream_t stream) {
  (void)in_sizes; (void)n_in; (void)out_size; (void)ws_size;
  const float* img    = (const float*)d_in[0];
  const float* pc2d   = (const float*)d_in[1];
  const float* Wq     = (const float*)d_in[2];
  const float* bq     = (const float*)d_in[3];
  const float* Wk     = (const float*)d_in[4];
  const float* bk     = (const float*)d_in[5];
  const float* Wvi    = (const float*)d_in[6];
  const float* bvi    = (const float*)d_in[7];
  const float* Wvp    = (const float*)d_in[8];
  const float* bvp    = (const float*)d_in[9];
  const float* gamma1 = (const float*)d_in[10];
  const float* W1     = (const float*)d_in[11];
  const float* b1     = (const float*)d_in[12];
  const float* W2     = (const float*)d_in[13];
  const float* b2     = (const float*)d_in[14];

  char* ws = (char*)d_ws;
  unsigned short* q_t   = (unsigned short*)(ws + 0);          // 16*4096*256 bf16 = 32 MB
  unsigned short* k_t   = (unsigned short*)(ws + 33554432);   // 32 MB
  unsigned short* wq_bf = (unsigned short*)(ws + 67108864);   // 128 KB
  unsigned short* wk_bf = (unsigned short*)(ws + 67239936);   // 1 MB
  float* row_m  = (float*)(ws + 68288512);                    // 16*4096 f32
  float* row_l  = (float*)(ws + 68550656);
  float* s_col  = (float*)(ws + 68812800);
  float* sbar   = (float*)(ws + 69074944);
  float* u_pool = (float*)(ws + 69075008);
  float* imean  = (float*)(ws + 69091392);
  float* t_pool = (float*)(ws + 69107776);
  float* fusedb = (float*)(ws + 69238848);
  float* h_buf  = (float*)(ws + 69386304);                    // ends at 69451840

  cvt_bf16<<<dim3(64), dim3(256), 0, stream>>>(Wq, wq_bf, 16384);
  cvt_bf16<<<dim3(512), dim3(256), 0, stream>>>(Wk, wk_bf, 131072);

  proj_kernel<<<dim3(64, 16), dim3(256), 0, stream>>>(img, wq_bf, bq, q_t, 256);
  proj_kernel<<<dim3(64, 16), dim3(256), 0, stream>>>(pc2d, wk_bf, bk, k_t, 2048);

  attn_rowstats<<<dim3(32, 16), dim3(256), 0, stream>>>(q_t, k_t, row_m, row_l);
  attn_colsum<<<dim3(32, 16), dim3(256), 0, stream>>>(q_t, k_t, row_m, row_l, s_col);

  sbar_kernel<<<dim3(16), dim3(256), 0, stream>>>(s_col, sbar);
  pool_kernel<<<dim3(36, 16), dim3(256), 0, stream>>>(img, pc2d, s_col, u_pool, imean, t_pool);

  imgfeat_kernel<<<dim3(4), dim3(256), 0, stream>>>(Wvi, bvi, gamma1, u_pool, imean, sbar, fusedb);
  pcfeat_kernel<<<dim3(32), dim3(256), 0, stream>>>(Wvp, bvp, t_pool, sbar, fusedb);

  head1_kernel<<<dim3(16), dim3(256), 0, stream>>>(W1, b1, fusedb, h_buf);
  head2_kernel<<<dim3(16), dim3(256), 0, stream>>>(W2, b2, h_buf, (float*)d_out);
}

// Round 2
// 1730.407 us; speedup vs baseline: 1.1469x; 1.1469x over previous
//
#include <hip/hip_runtime.h>
#include <cstdint>

typedef __attribute__((ext_vector_type(8))) short short8;
typedef __attribute__((ext_vector_type(4))) float f32x4;

#define LOG2E 1.44269504088896340736f
#define SHIFT 64.0f

__device__ __forceinline__ unsigned short f2bf(float x) {
  union { float f; unsigned u; } c; c.f = x;
  unsigned r = c.u + 0x7fffu + ((c.u >> 16) & 1u);
  return (unsigned short)(r >> 16);
}

// async global->LDS 16B/lane: HW writes lane l's data at lptr + l*16
__device__ __forceinline__ void gl2lds16(const void* g, void* l) {
  __builtin_amdgcn_global_load_lds((const __attribute__((address_space(1))) void*)g,
                                   (__attribute__((address_space(3))) void*)l, 16, 0, 0);
}

// ---------------------------------------------------------------------------
// K0: fp32 -> bf16 weight conversion (Wq, Wk)
// ---------------------------------------------------------------------------
__global__ void cvt_bf16(const float* __restrict__ src, unsigned short* __restrict__ dst, int n4) {
  int i = blockIdx.x * 256 + threadIdx.x;
  if (i >= n4) return;
  float4 v = ((const float4*)src)[i];
  ushort4 o;
  o.x = f2bf(v.x); o.y = f2bf(v.y); o.z = f2bf(v.z); o.w = f2bf(v.w);
  ((ushort4*)dst)[i] = o;
}

// ---------------------------------------------------------------------------
// Attention GEMM machinery: 128x128 tile, LDS [128 rows][64 cols] bf16,
// unpadded pitch 64 shorts, 16B granules XOR-swizzled: row r, position p
// holds global granule p ^ (r&7).  Staged via global_load_lds (src row
// stride = 256 shorts = 512B).
// ---------------------------------------------------------------------------
__device__ __forceinline__ void stage_tile_async(unsigned short* lds, const unsigned short* src,
                                                 int w, int lane) {
  const int r8 = lane >> 3;                  // row within 8-row group
  const int gx = (lane & 7) ^ r8;            // swizzled source granule
  const char* gbase = (const char*)src + (size_t)(w * 32 + r8) * 512 + gx * 16;
  char* lbase = (char*)lds + (w * 32) * 128;
#pragma unroll
  for (int p = 0; p < 4; ++p)
    gl2lds16(gbase + (size_t)p * 8 * 512, lbase + p * 1024);
}

__device__ __forceinline__ void mfma_step(const unsigned short* A, const unsigned short* B,
                                          int aBase, int bBase, const int poff0, const int poff1,
                                          f32x4 acc[4][4]) {
#pragma unroll
  for (int ks = 0; ks < 2; ++ks) {
    const int po = ks ? poff1 : poff0;
    short8 af[4], bfr[4];
#pragma unroll
    for (int mt = 0; mt < 4; ++mt) af[mt] = *(const short8*)&A[aBase + mt * 1024 + po];
#pragma unroll
    for (int nt = 0; nt < 4; ++nt) bfr[nt] = *(const short8*)&B[bBase + nt * 1024 + po];
#pragma unroll
    for (int mt = 0; mt < 4; ++mt)
#pragma unroll
      for (int nt = 0; nt < 4; ++nt)
        acc[mt][nt] = __builtin_amdgcn_mfma_f32_16x16x32_bf16(af[mt], bfr[nt], acc[mt][nt], 0, 0, 0);
  }
}

// ---------------------------------------------------------------------------
// K2: row sums  l_i = sum_j exp2(S_ij*log2e - 64).  WG = (b, 128 q-rows).
// ---------------------------------------------------------------------------
__global__ __launch_bounds__(256, 2) void attn_rowsum(
    const unsigned short* __restrict__ qt, const unsigned short* __restrict__ kt,
    float* __restrict__ row_l) {
  __shared__ unsigned short Ab[2][128 * 64];
  __shared__ unsigned short Bb[2][128 * 64];
  __shared__ float lred[2][128];
  const int b = blockIdx.y, i0 = blockIdx.x * 128;
  const int t = threadIdx.x, w = t >> 6, lane = t & 63, q = lane >> 4, ln = lane & 15;
  const int ihalf = w >> 1, jhalf = w & 1;
  const unsigned short* qbase = qt + ((size_t)b * 4096 + i0) * 256;
  const unsigned short* kbase = kt + (size_t)b * 4096 * 256;
  const int poff0 = ((q) ^ (ln & 7)) * 8;
  const int poff1 = ((4 + q) ^ (ln & 7)) * 8;
  const int aBase = (ihalf * 64 + ln) * 64;
  const int bBase = (jhalf * 64 + ln) * 64;
  float lacc[4][4] = {};

  stage_tile_async(Ab[0], qbase, w, lane);
  stage_tile_async(Bb[0], kbase, w, lane);
  __syncthreads();

  for (int jt = 0; jt < 32; ++jt) {
    f32x4 acc[4][4] = {};
#pragma unroll 1
    for (int ch = 0; ch < 4; ++ch) {
      const int s = jt * 4 + ch;
      if (s + 1 < 128) {
        const int jn = (s + 1) >> 2, cn = (s + 1) & 3;
        stage_tile_async(Ab[(s + 1) & 1], qbase + cn * 64, w, lane);
        stage_tile_async(Bb[(s + 1) & 1], kbase + (size_t)jn * 128 * 256 + cn * 64, w, lane);
      }
      mfma_step(Ab[s & 1], Bb[s & 1], aBase, bBase, poff0, poff1, acc);
      __syncthreads();
    }
    // epilogue (register-only): per-row partial sumexp over this 128-j tile
#pragma unroll
    for (int mt = 0; mt < 4; ++mt)
#pragma unroll
      for (int r = 0; r < 4; ++r) {
        float e = exp2f(acc[mt][0][r] * LOG2E - SHIFT) + exp2f(acc[mt][1][r] * LOG2E - SHIFT)
                + exp2f(acc[mt][2][r] * LOG2E - SHIFT) + exp2f(acc[mt][3][r] * LOG2E - SHIFT);
        e += __shfl_xor(e, 1); e += __shfl_xor(e, 2);
        e += __shfl_xor(e, 4); e += __shfl_xor(e, 8);
        lacc[mt][r] += e;
      }
  }
  if (ln == 0) {
#pragma unroll
    for (int mt = 0; mt < 4; ++mt)
#pragma unroll
      for (int r = 0; r < 4; ++r)
        lred[jhalf][ihalf * 64 + mt * 16 + q * 4 + r] = lacc[mt][r];
  }
  __syncthreads();
  if (t < 128) row_l[b * 4096 + i0 + t] = lred[0][t] + lred[1][t];
}

// ---------------------------------------------------------------------------
// linv = 1/l
// ---------------------------------------------------------------------------
__global__ void inv_kernel(const float* __restrict__ l, float* __restrict__ linv) {
  int i = blockIdx.x * 256 + threadIdx.x;
  linv[i] = 1.0f / l[i];
}

// ---------------------------------------------------------------------------
// K3: column sums  s_j = sum_i exp2(S_ij*log2e - 64) * linv_i.
// WG = (b, 128 k-cols); streams 32 q-tiles.
// ---------------------------------------------------------------------------
__global__ __launch_bounds__(256, 2) void attn_colsum(
    const unsigned short* __restrict__ qt, const unsigned short* __restrict__ kt,
    const float* __restrict__ linv, float* __restrict__ s_col) {
  __shared__ unsigned short Ab[2][128 * 64];
  __shared__ unsigned short Bb[2][128 * 64];
  __shared__ float sred[2][128];
  const int b = blockIdx.y, j0 = blockIdx.x * 128;
  const int t = threadIdx.x, w = t >> 6, lane = t & 63, q = lane >> 4, ln = lane & 15;
  const int ihalf = w >> 1, jhalf = w & 1;
  const unsigned short* qbase = qt + (size_t)b * 4096 * 256;
  const unsigned short* kb = kt + ((size_t)b * 4096 + j0) * 256;
  const int poff0 = ((q) ^ (ln & 7)) * 8;
  const int poff1 = ((4 + q) ^ (ln & 7)) * 8;
  const int aBase = (ihalf * 64 + ln) * 64;
  const int bBase = (jhalf * 64 + ln) * 64;
  float scacc[4] = {};

  stage_tile_async(Ab[0], qbase, w, lane);
  stage_tile_async(Bb[0], kb, w, lane);
  __syncthreads();

  for (int it = 0; it < 32; ++it) {
    // per-row 1/l for this q-tile (broadcast across ln; issued early)
    const float4* lp = (const float4*)(linv + (size_t)b * 4096 + it * 128 + ihalf * 64 + q * 4);
    float4 lv[4];
#pragma unroll
    for (int mt = 0; mt < 4; ++mt) lv[mt] = lp[mt * 4];

    f32x4 acc[4][4] = {};
#pragma unroll 1
    for (int ch = 0; ch < 4; ++ch) {
      const int s = it * 4 + ch;
      if (s + 1 < 128) {
        const int in_ = (s + 1) >> 2, cn = (s + 1) & 3;
        stage_tile_async(Ab[(s + 1) & 1], qbase + (size_t)in_ * 128 * 256 + cn * 64, w, lane);
        stage_tile_async(Bb[(s + 1) & 1], kb + cn * 64, w, lane);
      }
      mfma_step(Ab[s & 1], Bb[s & 1], aBase, bBase, poff0, poff1, acc);
      __syncthreads();
    }
#pragma unroll
    for (int nt = 0; nt < 4; ++nt) {
      float v = 0.f;
#pragma unroll
      for (int mt = 0; mt < 4; ++mt) {
        v += exp2f(acc[mt][nt][0] * LOG2E - SHIFT) * lv[mt].x;
        v += exp2f(acc[mt][nt][1] * LOG2E - SHIFT) * lv[mt].y;
        v += exp2f(acc[mt][nt][2] * LOG2E - SHIFT) * lv[mt].z;
        v += exp2f(acc[mt][nt][3] * LOG2E - SHIFT) * lv[mt].w;
      }
      v += __shfl_xor(v, 16); v += __shfl_xor(v, 32);
      scacc[nt] += v;
    }
  }
  if (q == 0) {
#pragma unroll
    for (int nt = 0; nt < 4; ++nt)
      sred[ihalf][jhalf * 64 + nt * 16 + ln] = scacc[nt];
  }
  __syncthreads();
  if (t < 128) s_col[b * 4096 + j0 + t] = sred[0][t] + sred[1][t];
}

// ---------------------------------------------------------------------------
// K1: projection  Out[b][sp][co] = sum_ci In[b][ci][sp] * W[co][ci] + bias[co]
// ---------------------------------------------------------------------------
__global__ __launch_bounds__(256, 2) void proj_kernel(
    const float* __restrict__ In, const unsigned short* __restrict__ Wbf,
    const float* __restrict__ bias, unsigned short* __restrict__ Out, int Kdim) {
  __shared__ unsigned short Alds[64 * 72];
  __shared__ unsigned short Blds[256 * 72];
  const int b = blockIdx.y, sp0 = blockIdx.x * 64;
  const int t = threadIdx.x, w = t >> 6, lane = t & 63, q = lane >> 4, ln = lane & 15;
  f32x4 acc[4][4] = {};
  const int nch = Kdim >> 6;
  for (int ch = 0; ch < nch; ++ch) {
    const int ci0 = ch * 64;
    // stage B = W rows [256 co][64 ci]
#pragma unroll
    for (int p = 0; p < 8; ++p) {
      int s = t + 256 * p;
      int row = s >> 3, sl = s & 7;
      *(uint4*)(&Blds[row * 72 + sl * 8]) = *(const uint4*)(&Wbf[(size_t)row * Kdim + ci0 + sl * 8]);
    }
    // stage A = In^T tile [64 sp][64 ci]; coalesced reads: 8 lanes x 32B per ci row
    {
      const int cp = t >> 3, spg = t & 7;
      const float* r0 = In + ((size_t)b * Kdim + ci0 + 2 * cp) * 4096 + sp0 + spg * 8;
      const float* r1 = r0 + 4096;
      float4 a0 = *(const float4*)(r0);
      float4 a1 = *(const float4*)(r0 + 4);
      float4 b0 = *(const float4*)(r1);
      float4 b1 = *(const float4*)(r1 + 4);
      float va[8] = {a0.x, a0.y, a0.z, a0.w, a1.x, a1.y, a1.z, a1.w};
      float vb[8] = {b0.x, b0.y, b0.z, b0.w, b1.x, b1.y, b1.z, b1.w};
#pragma unroll
      for (int k2 = 0; k2 < 8; ++k2) {
        unsigned u0 = f2bf(va[k2]), u1 = f2bf(vb[k2]);
        *(unsigned*)(&Alds[(spg * 8 + k2) * 72 + 2 * cp]) = u0 | (u1 << 16);
      }
    }
    __syncthreads();
#pragma unroll
    for (int ks = 0; ks < 2; ++ks) {
      short8 af[4], bfr[4];
#pragma unroll
      for (int mt = 0; mt < 4; ++mt)
        af[mt] = *(const short8*)(&Alds[(mt * 16 + ln) * 72 + ks * 32 + q * 8]);
#pragma unroll
      for (int nt = 0; nt < 4; ++nt)
        bfr[nt] = *(const short8*)(&Blds[(w * 64 + nt * 16 + ln) * 72 + ks * 32 + q * 8]);
#pragma unroll
      for (int mt = 0; mt < 4; ++mt)
#pragma unroll
        for (int nt = 0; nt < 4; ++nt)
          acc[mt][nt] = __builtin_amdgcn_mfma_f32_16x16x32_bf16(af[mt], bfr[nt], acc[mt][nt], 0, 0, 0);
    }
    __syncthreads();
  }
#pragma unroll
  for (int nt = 0; nt < 4; ++nt) {
    int co = w * 64 + nt * 16 + ln;
    float bv = bias[co];
#pragma unroll
    for (int mt = 0; mt < 4; ++mt)
#pragma unroll
      for (int r = 0; r < 4; ++r) {
        int sp = sp0 + mt * 16 + q * 4 + r;
        Out[((size_t)b * 4096 + sp) * 256 + co] = f2bf(acc[mt][nt][r] + bv);
      }
  }
}

// ---------------------------------------------------------------------------
// sbar[b] = sum_n s[b][n] / 4096
// ---------------------------------------------------------------------------
__global__ void sbar_kernel(const float* __restrict__ s_col, float* __restrict__ sbar) {
  const int b = blockIdx.x, t = threadIdx.x;
  float v = 0.f;
  for (int k = 0; k < 16; ++k) v += s_col[b * 4096 + t + 256 * k];
  for (int m = 1; m < 64; m <<= 1) v += __shfl_xor(v, m);
  __shared__ float red[4];
  if ((t & 63) == 0) red[t >> 6] = v;
  __syncthreads();
  if (t == 0) sbar[b] = (red[0] + red[1] + red[2] + red[3]) * (1.f / 4096.f);
}

// ---------------------------------------------------------------------------
// K4: pooling. chunk<4 -> img channels (u & imean); else pc2d channels (t).
// ---------------------------------------------------------------------------
__global__ void pool_kernel(const float* __restrict__ img, const float* __restrict__ pc2d,
                            const float* __restrict__ s_col, float* __restrict__ u_pool,
                            float* __restrict__ imean, float* __restrict__ t_pool) {
  const int b = blockIdx.y, chunk = blockIdx.x;
  const int t = threadIdx.x, ch_l = t >> 2, j = t & 3;
  const bool isimg = chunk < 4;
  int ch;
  const float4* row4;
  if (isimg) {
    ch = chunk * 64 + ch_l;
    row4 = (const float4*)(img + ((size_t)b * 256 + ch) * 4096);
  } else {
    ch = (chunk - 4) * 64 + ch_l;
    row4 = (const float4*)(pc2d + ((size_t)b * 2048 + ch) * 4096);
  }
  const float4* s4 = (const float4*)(s_col + b * 4096);
  float accd = 0.f, accs = 0.f;
  for (int kk = 0; kk < 256; ++kk) {
    float4 x = row4[j + 4 * kk];
    float4 sv = s4[j + 4 * kk];
    accd += x.x * sv.x + x.y * sv.y + x.z * sv.z + x.w * sv.w;
    accs += x.x + x.y + x.z + x.w;
  }
  accd += __shfl_xor(accd, 1); accd += __shfl_xor(accd, 2);
  accs += __shfl_xor(accs, 1); accs += __shfl_xor(accs, 2);
  if (j == 0) {
    if (isimg) {
      u_pool[b * 256 + ch] = accd * (1.f / 4096.f);
      imean[b * 256 + ch] = accs * (1.f / 4096.f);
    } else {
      t_pool[b * 2048 + ch] = accd * (1.f / 4096.f);
    }
  }
}

// ---------------------------------------------------------------------------
// img_feat -> fused[0:256]
// ---------------------------------------------------------------------------
__global__ void imgfeat_kernel(const float* __restrict__ Wvi, const float* __restrict__ bvi,
                               const float* __restrict__ gamma1, const float* __restrict__ u_pool,
                               const float* __restrict__ imean, const float* __restrict__ sbar,
                               float* __restrict__ fused) {
  const int t = threadIdx.x;
  const int co = blockIdx.x * 64 + (t >> 2), j = t & 3;
  float acc[16];
#pragma unroll
  for (int b = 0; b < 16; ++b) acc[b] = 0.f;
  const float4* w4 = (const float4*)(Wvi + (size_t)co * 256);
  for (int kk = 0; kk < 16; ++kk) {
    float4 wv = w4[j + 4 * kk];
#pragma unroll
    for (int b = 0; b < 16; ++b) {
      float4 uv = ((const float4*)(u_pool + b * 256))[j + 4 * kk];
      acc[b] += wv.x * uv.x + wv.y * uv.y + wv.z * uv.z + wv.w * uv.w;
    }
  }
#pragma unroll
  for (int b = 0; b < 16; ++b) { acc[b] += __shfl_xor(acc[b], 1); acc[b] += __shfl_xor(acc[b], 2); }
  if (j == 0) {
    float g = gamma1[0], bv = bvi[co];
#pragma unroll
    for (int b = 0; b < 16; ++b)
      fused[b * 2304 + co] = g * (acc[b] + bv * sbar[b]) + imean[b * 256 + co];
  }
}

// ---------------------------------------------------------------------------
// pc_feat -> fused[256:2304]
// ---------------------------------------------------------------------------
__global__ void pcfeat_kernel(const float* __restrict__ Wvp, const float* __restrict__ bvp,
                              const float* __restrict__ t_pool, const float* __restrict__ sbar,
                              float* __restrict__ fused) {
  const int t = threadIdx.x;
  const int co = blockIdx.x * 64 + (t >> 2), j = t & 3;
  float acc[16];
#pragma unroll
  for (int b = 0; b < 16; ++b) acc[b] = 0.f;
  const float4* w4 = (const float4*)(Wvp + (size_t)co * 2048);
  for (int kk = 0; kk < 128; ++kk) {
    float4 wv = w4[j + 4 * kk];
#pragma unroll
    for (int b = 0; b < 16; ++b) {
      float4 tv = ((const float4*)(t_pool + b * 2048))[j + 4 * kk];
      acc[b] += wv.x * tv.x + wv.y * tv.y + wv.z * tv.z + wv.w * tv.w;
    }
  }
#pragma unroll
  for (int b = 0; b < 16; ++b) { acc[b] += __shfl_xor(acc[b], 1); acc[b] += __shfl_xor(acc[b], 2); }
  if (j == 0) {
    float bv = bvp[co];
#pragma unroll
    for (int b = 0; b < 16; ++b)
      fused[b * 2304 + 256 + co] = acc[b] + bv * sbar[b];
  }
}

// ---------------------------------------------------------------------------
// h = relu(fused @ W1^T + b1)
// ---------------------------------------------------------------------------
__global__ void head1_kernel(const float* __restrict__ W1, const float* __restrict__ b1,
                             const float* __restrict__ fused, float* __restrict__ h) {
  const int t = threadIdx.x;
  const int o = blockIdx.x * 64 + (t >> 2), j = t & 3;
  float acc[16];
#pragma unroll
  for (int b = 0; b < 16; ++b) acc[b] = 0.f;
  const float4* w4 = (const float4*)(W1 + (size_t)o * 2304);
  for (int kk = 0; kk < 144; ++kk) {
    float4 wv = w4[j + 4 * kk];
#pragma unroll
    for (int b = 0; b < 16; ++b) {
      float4 fv = ((const float4*)(fused + b * 2304))[j + 4 * kk];
      acc[b] += wv.x * fv.x + wv.y * fv.y + wv.z * fv.z + wv.w * fv.w;
    }
  }
#pragma unroll
  for (int b = 0; b < 16; ++b) { acc[b] += __shfl_xor(acc[b], 1); acc[b] += __shfl_xor(acc[b], 2); }
  if (j == 0) {
    float bv = b1[o];
#pragma unroll
    for (int b = 0; b < 16; ++b) h[b * 1024 + o] = fmaxf(acc[b] + bv, 0.f);
  }
}

// ---------------------------------------------------------------------------
// logits + log_softmax -> out[b][40]
// ---------------------------------------------------------------------------
__global__ void head2_kernel(const float* __restrict__ W2, const float* __restrict__ b2,
                             const float* __restrict__ h, float* __restrict__ out) {
  const int b = blockIdx.x, t = threadIdx.x;
  __shared__ float logit[40];
  __shared__ float red[4];
  float4 hv = ((const float4*)(h + b * 1024))[t];
  for (int c = 0; c < 40; ++c) {
    float4 wv = ((const float4*)(W2 + (size_t)c * 1024))[t];
    float p = wv.x * hv.x + wv.y * hv.y + wv.z * hv.z + wv.w * hv.w;
    for (int m = 1; m < 64; m <<= 1) p += __shfl_xor(p, m);
    if ((t & 63) == 0) red[t >> 6] = p;
    __syncthreads();
    if (t == 0) logit[c] = red[0] + red[1] + red[2] + red[3] + b2[c];
    __syncthreads();
  }
  if (t == 0) {
    float mx = -1e30f;
    for (int c = 0; c < 40; ++c) mx = fmaxf(mx, logit[c]);
    float s = 0.f;
    for (int c = 0; c < 40; ++c) s += expf(logit[c] - mx);
    float ls = logf(s);
    for (int c = 0; c < 40; ++c) out[b * 40 + c] = logit[c] - mx - ls;
  }
}

// ---------------------------------------------------------------------------
extern "C" void kernel_launch(void* const* d_in, const int* in_sizes, int n_in,
                              void* d_out, int out_size, void* d_ws, size_t ws_size,
                              hipStream_t stream) {
  (void)in_sizes; (void)n_in; (void)out_size; (void)ws_size;
  const float* img    = (const float*)d_in[0];
  const float* pc2d   = (const float*)d_in[1];
  const float* Wq     = (const float*)d_in[2];
  const float* bq     = (const float*)d_in[3];
  const float* Wk     = (const float*)d_in[4];
  const float* bk     = (const float*)d_in[5];
  const float* Wvi    = (const float*)d_in[6];
  const float* bvi    = (const float*)d_in[7];
  const float* Wvp    = (const float*)d_in[8];
  const float* bvp    = (const float*)d_in[9];
  const float* gamma1 = (const float*)d_in[10];
  const float* W1     = (const float*)d_in[11];
  const float* b1     = (const float*)d_in[12];
  const float* W2     = (const float*)d_in[13];
  const float* b2     = (const float*)d_in[14];

  char* ws = (char*)d_ws;
  unsigned short* q_t   = (unsigned short*)(ws + 0);          // 32 MB
  unsigned short* k_t   = (unsigned short*)(ws + 33554432);   // 32 MB
  unsigned short* wq_bf = (unsigned short*)(ws + 67108864);   // 128 KB
  unsigned short* wk_bf = (unsigned short*)(ws + 67239936);   // 1 MB
  float* linv   = (float*)(ws + 68288512);                    // 16*4096 f32
  float* row_l  = (float*)(ws + 68550656);
  float* s_col  = (float*)(ws + 68812800);
  float* sbar   = (float*)(ws + 69074944);
  float* u_pool = (float*)(ws + 69075008);
  float* imean  = (float*)(ws + 69091392);
  float* t_pool = (float*)(ws + 69107776);
  float* fusedb = (float*)(ws + 69238848);
  float* h_buf  = (float*)(ws + 69386304);

  cvt_bf16<<<dim3(64), dim3(256), 0, stream>>>(Wq, wq_bf, 16384);
  cvt_bf16<<<dim3(512), dim3(256), 0, stream>>>(Wk, wk_bf, 131072);

  proj_kernel<<<dim3(64, 16), dim3(256), 0, stream>>>(img, wq_bf, bq, q_t, 256);
  proj_kernel<<<dim3(64, 16), dim3(256), 0, stream>>>(pc2d, wk_bf, bk, k_t, 2048);

  attn_rowsum<<<dim3(32, 16), dim3(256), 0, stream>>>(q_t, k_t, row_l);
  inv_kernel<<<dim3(256), dim3(256), 0, stream>>>(row_l, linv);
  attn_colsum<<<dim3(32, 16), dim3(256), 0, stream>>>(q_t, k_t, linv, s_col);

  sbar_kernel<<<dim3(16), dim3(256), 0, stream>>>(s_col, sbar);
  pool_kernel<<<dim3(36, 16), dim3(256), 0, stream>>>(img, pc2d, s_col, u_pool, imean, t_pool);

  imgfeat_kernel<<<dim3(4), dim3(256), 0, stream>>>(Wvi, bvi, gamma1, u_pool, imean, sbar, fusedb);
  pcfeat_kernel<<<dim3(32), dim3(256), 0, stream>>>(Wvp, bvp, t_pool, sbar, fusedb);

  head1_kernel<<<dim3(16), dim3(256), 0, stream>>>(W1, b1, fusedb, h_buf);
  head2_kernel<<<dim3(16), dim3(256), 0, stream>>>(W2, b2, h_buf, (float*)d_out);
}